// Round 8
// baseline (910.062 us; speedup 1.0000x reference)
//
#include <hip/hip_runtime.h>
#include <stdint.h>

#define AS1 __attribute__((address_space(1)))
#define AS3 __attribute__((address_space(3)))

typedef _Float16 f16x8 __attribute__((ext_vector_type(8)));
typedef float f32x4 __attribute__((ext_vector_type(4)));

__device__ __forceinline__ unsigned short f32_f16(float f) {
  union { _Float16 h; unsigned short u; } v; v.h = (_Float16)f; return v.u;
}
__device__ __forceinline__ float f16_f32(unsigned short u) {
  union { _Float16 h; unsigned short u; } v; v.u = u; return (float)v.h;
}
// plain staging (L1+L2 cached) — for the GEMM
__device__ __forceinline__ void gl_lds16(const unsigned short* g, unsigned short* l) {
  __builtin_amdgcn_global_load_lds((const AS1 unsigned int*)g, (AS3 unsigned int*)l, 16, 0, 0);
}
// sc0 scalar load: bypass L1, read own-XCD L2 (R10-proven instruction)
__device__ __forceinline__ unsigned ld_sc0(const unsigned* p) {
  unsigned v;
  asm volatile("global_load_dword %0, %1, off sc0\n\ts_waitcnt vmcnt(0)"
               : "=v"(v) : "v"(p) : "memory");
  return v;
}
// sc0 store: write through L1 to own-XCD L2, leave line valid there (proven)
__device__ __forceinline__ void st_sc0(unsigned* p, unsigned v) {
  asm volatile("global_store_dword %0, %1, off sc0" :: "v"(p), "v"(v) : "memory");
}

// ---------------- fused f32 -> fp16 conversion (facts, Wr, W, mem_old) ----------
__global__ void cvt_all(const float4* __restrict__ sf, ushort4* __restrict__ df,
                        const float4* __restrict__ s1, ushort4* __restrict__ d1,
                        const float4* __restrict__ s2, ushort4* __restrict__ d2,
                        const float4* __restrict__ sm, ushort4* __restrict__ dm) {
  int i = blockIdx.x * blockDim.x + threadIdx.x;
  int st = gridDim.x * blockDim.x;
  for (int k = i; k < 4751360; k += st) {
    const float4* s; ushort4* d; int off;
    if (k < 4194304)      { s = sf; d = df; off = k; }
    else if (k < 4456448) { s = s1; d = d1; off = k - 4194304; }
    else if (k < 4718592) { s = s2; d = d2; off = k - 4456448; }
    else                  { s = sm; d = dm; off = k - 4718592; }
    float4 v = s[off];
    ushort4 o;
    o.x = f32_f16(v.x); o.y = f32_f16(v.y); o.z = f32_f16(v.z); o.w = f32_f16(v.w);
    d[off] = o;
  }
}

// ---------------- phase 1: C[t][b][0:2048] = facts(b,t,:) @ [Wr|W]^T (fp16 out) ----
// BK=64 (16 K-tiles), XOR source-swizzle staging, scalar C-store (proven R9/R11).
__global__ __launch_bounds__(256, 2) void gemm_fw(
    const unsigned short* __restrict__ A,
    const unsigned short* __restrict__ Bt,
    unsigned short* __restrict__ Ct)
{
  __shared__ __align__(16) unsigned short As[128 * 64];
  __shared__ __align__(16) unsigned short Bs[128 * 64];
  const int tid = threadIdx.x;
  const int lane = tid & 63;
  const int wv = tid >> 6;
  const int q = lane >> 4, ln = lane & 15;
  const int bm = blockIdx.x, bn = blockIdx.y;
  const int wm = (wv >> 1) * 64, wn = (wv & 1) * 64;

  f32x4 acc[4][4] = {};

  for (int kt = 0; kt < 1024; kt += 64) {
    __syncthreads();
#pragma unroll
    for (int rr = 0; rr < 4; ++rr) {
      int chunk = rr * 256 + tid;          // 0..1023
      int r = chunk >> 3, c = chunk & 7;   // 8 chunks (16B) per 128B row
      int cs = c ^ (r & 7);                // source chunk for this LDS pos
      gl_lds16(A + (size_t)(bm * 128 + r) * 1024 + kt + cs * 8, As + chunk * 8);
      gl_lds16(Bt + (size_t)(bn * 128 + r) * 1024 + kt + cs * 8, Bs + chunk * 8);
    }
    __syncthreads();
    f16x8 af[4][2], bfr[4][2];
#pragma unroll
    for (int mi = 0; mi < 4; ++mi)
#pragma unroll
      for (int kk = 0; kk < 2; ++kk)
        af[mi][kk] = *(const f16x8*)(As + (wm + mi * 16 + ln) * 64 + (((q + 4 * kk) ^ (ln & 7)) * 8));
#pragma unroll
    for (int ni = 0; ni < 4; ++ni)
#pragma unroll
      for (int kk = 0; kk < 2; ++kk)
        bfr[ni][kk] = *(const f16x8*)(Bs + (wn + ni * 16 + ln) * 64 + (((q + 4 * kk) ^ (ln & 7)) * 8));
#pragma unroll
    for (int kk = 0; kk < 2; ++kk)
#pragma unroll
      for (int mi = 0; mi < 4; ++mi)
#pragma unroll
        for (int ni = 0; ni < 4; ++ni)
          acc[mi][ni] = __builtin_amdgcn_mfma_f32_16x16x32_f16(af[mi][kk], bfr[ni][kk], acc[mi][ni], 0, 0, 0);
  }
#pragma unroll
  for (int mi = 0; mi < 4; ++mi)
#pragma unroll
    for (int ni = 0; ni < 4; ++ni)
#pragma unroll
      for (int r2 = 0; r2 < 4; ++r2) {
        int trow = wm + mi * 16 + q * 4 + r2;   // == t
        int col = bn * 128 + wn + ni * 16 + ln; // 0..2047: [fWr | fW]
        Ct[(size_t)trow * 262144 + (size_t)bm * 2048 + col] = f32_f16(acc[mi][ni][r2]);
      }
}

// ---------------- phase 2: the recurrence (LDS-free A path, direct L2->VGPR) ----
// Grid 256 = 8 groups x 32 dim-slices; 4 waves, one matrix per wave-pair.
// R6 post-mortem: SQ_LDS_BANK_CONFLICT is the gl_lds WRITE port, not reads —
// the staging mechanism itself is the cost. This version deletes it: each
// lane's A-fragment is 16 contiguous bytes of hbf -> global_load_dwordx4 sc0
// straight to VGPRs (same R10-proven sc0 pair as the flags; fallback sc0 sc1
// reads IC). Pipelined in 4 groups of 8 with counted vmcnt(8): issue G0,G1 ->
// wait8 -> MFMA G0 -> issue G2 -> wait8 -> MFMA G1 -> ... ONE barrier/step
// (xchg handoff, parity-double-buffered). fwx(t+1) issued before the poll,
// absorbed by the poll's inline vmcnt(0). sched_barrier(0) after every
// waitcnt (rule #18). Per-wave flags + single poll from R5 unchanged.
// NOTE: asm operand order is `off offset:N sc0` — flags AFTER the offset
// (R7 compile fail: `off sc0 offset:N` does not assemble on gfx950).
#define MF(A_, B_, C_) __builtin_amdgcn_mfma_f32_16x16x32_f16(A_, B_, C_, 0, 0, 0)
#define LDAF(d, off) asm volatile("global_load_dwordx4 %0, %1, off offset:" off " sc0" : "=v"(d) : "v"(hA) : "memory")
#define LDAC(d, off) asm volatile("global_load_dwordx4 %0, %1, off offset:" off " sc0 sc1" : "=v"(d) : "v"(hA) : "memory")
#define SB __builtin_amdgcn_sched_barrier(0)

__global__ __launch_bounds__(256, 1) void gru_recur(
    const unsigned short* __restrict__ fwx,   // [128 t][128 b][2048] f16
    const float* __restrict__ Urw, const float* __restrict__ Urb,
    const float* __restrict__ Uw,  const float* __restrict__ Ub,
    const float* __restrict__ g,              // [128 b][128 t]
    const float* __restrict__ mem_old,        // [128][1024]
    const int* __restrict__ nfp,              // [128]
    unsigned short* __restrict__ hbf,         // [2][128][1024] f16
    unsigned int* __restrict__ flg,           // [8 ga][32 blk][2 wave][16 pad] u32
    unsigned int* __restrict__ xcc,           // [8 ga][32 blk][32 pad] u32
    float* __restrict__ out)                  // [128][1024] f32
{
  __shared__ float xchg[2][512];              // parity double-buffered handoff
  __shared__ int fast_lds;

  const int tid = threadIdx.x;
  const int lane = tid & 63;
  const int w = tid >> 6;
  const int q = lane >> 4;
  const int ln = lane & 15;
  const int matrix = w >> 1;
  const int ntile = w & 1;
  const int ga = blockIdx.x & 7;    // XCD-local group under round-robin dispatch
  const int dsl = blockIdx.x >> 3;  // dim-slice within group, 0..31
  const int b0 = ga * 16;
  const int n_g = dsl * 32 + ntile * 16 + ln;

  // --- XCD-uniformity handshake (R10-proven, over the always-correct IC path) ---
  unsigned my_xcc;
  asm("s_getreg_b32 %0, hwreg(HW_REG_XCC_ID)" : "=s"(my_xcc));
  if (tid == 0)
    __hip_atomic_store(&xcc[(ga * 32 + dsl) * 32], my_xcc + 1u,
                       __ATOMIC_RELAXED, __HIP_MEMORY_SCOPE_AGENT);
  if (w == 0) {
    unsigned* xp = &xcc[(ga * 32 + (lane & 31)) * 32];
    unsigned v;
    for (;;) {
      v = __hip_atomic_load(xp, __ATOMIC_RELAXED, __HIP_MEMORY_SCOPE_AGENT);
      if (__ballot(lane < 32 && v == 0u) == 0ull) break;
    }
    unsigned long long bad = __ballot(lane < 32 && v != my_xcc + 1u);
    if (lane == 0) fast_lds = (bad == 0ull);
  }

  // --- one-time: weights into registers (B-fragment layout: n=lane&15, k=q*8+j) ---
  const float* Wm = matrix ? Uw : Urw;
  f16x8 bw[32];
#pragma unroll
  for (int ks = 0; ks < 32; ++ks) {
    const float* s = Wm + (size_t)n_g * 1024 + ks * 32 + q * 8;
    float4 x0 = *(const float4*)s;
    float4 x1 = *(const float4*)(s + 4);
    f16x8 t;
    t[0] = (_Float16)x0.x; t[1] = (_Float16)x0.y;
    t[2] = (_Float16)x0.z; t[3] = (_Float16)x0.w;
    t[4] = (_Float16)x1.x; t[5] = (_Float16)x1.y;
    t[6] = (_Float16)x1.z; t[7] = (_Float16)x1.w;
    bw[ks] = t;
  }
  const float bias = (matrix ? Ub : Urb)[n_g];
  const f32x4 zero4 = {0.f, 0.f, 0.f, 0.f};
  f32x4 acc0 = {bias, bias, bias, bias};   // ks%4==0 chain (carries the bias)
  f32x4 acc1 = zero4, acc2 = zero4, acc3 = zero4;

  float h_own[4] = {0.f, 0.f, 0.f, 0.f};
  int nf[4] = {0, 0, 0, 0};
  if (matrix == 0) {
#pragma unroll
    for (int r = 0; r < 4; ++r) {
      int b = b0 + q * 4 + r;
      h_own[r] = mem_old[(size_t)b * 1024 + n_g];
      nf[r] = nfp[b];
    }
  }

  __syncthreads();
  const int fast = fast_lds;

  // A-load base: lane reads h[b0+ln][ks*32 + q*8 .. +8] = 16B at offset ks*64
  const unsigned short* hA0 = hbf + (size_t)(b0 + ln) * 1024 + q * 8;
  const unsigned short* hA1 = hA0 + 131072;

  // per-wave flag (producers = m0 waves); poll maps 64 lanes -> 64 flags
  unsigned int* myf = flg + ((size_t)((ga * 32 + dsl) * 2 + ntile)) * 16;
  unsigned int* fp  = flg + ((size_t)((ga * 32 + (lane >> 1)) * 2 + (lane & 1))) * 16;

  // epilogue operands carried as RAW u16 (loads stay in flight until epilogue)
  unsigned short fwru[4] = {0, 0, 0, 0}, fwu[4] = {0, 0, 0, 0};
  float gvv[4] = {0.f, 0.f, 0.f, 0.f};

  // prologue: fwx(0)/g(0) prefetch (drained by the first MFMA-phase waits)
  if (matrix == 0) {
#pragma unroll
    for (int r = 0; r < 4; ++r) {
      int b = b0 + q * 4 + r;
      size_t base = (size_t)b * 2048;   // t = 0
      fwru[r] = fwx[base + n_g];
      fwu[r]  = fwx[base + 1024 + n_g];
      gvv[r]  = g[b * 128 + 0];
    }
  }
  SB;

  f16x8 aa0, aa1, aa2, aa3, aa4, aa5, aa6, aa7;   // ping
  f16x8 ab0, ab1, ab2, ab3, ab4, ab5, ab6, ab7;   // pong

  for (int t = 0; t < 128; ++t) {
    const unsigned short* hA = (t & 1) ? hA1 : hA0;

    // ---- MFMA phase: 4 groups of 8 ks, loads pipelined 1 group ahead ----
    if (fast) { LDAF(aa0,"0");    LDAF(aa1,"64");   LDAF(aa2,"128");  LDAF(aa3,"192");
                LDAF(aa4,"256");  LDAF(aa5,"320");  LDAF(aa6,"384");  LDAF(aa7,"448"); }
    else      { LDAC(aa0,"0");    LDAC(aa1,"64");   LDAC(aa2,"128");  LDAC(aa3,"192");
                LDAC(aa4,"256");  LDAC(aa5,"320");  LDAC(aa6,"384");  LDAC(aa7,"448"); }
    SB;
    if (fast) { LDAF(ab0,"512");  LDAF(ab1,"576");  LDAF(ab2,"640");  LDAF(ab3,"704");
                LDAF(ab4,"768");  LDAF(ab5,"832");  LDAF(ab6,"896");  LDAF(ab7,"960"); }
    else      { LDAC(ab0,"512");  LDAC(ab1,"576");  LDAC(ab2,"640");  LDAC(ab3,"704");
                LDAC(ab4,"768");  LDAC(ab5,"832");  LDAC(ab6,"896");  LDAC(ab7,"960"); }
    SB;
    asm volatile("s_waitcnt vmcnt(8)" ::: "memory"); SB;   // G0 landed
    acc0 = MF(aa0, bw[0], acc0);  acc1 = MF(aa1, bw[1], acc1);
    acc2 = MF(aa2, bw[2], acc2);  acc3 = MF(aa3, bw[3], acc3);
    acc0 = MF(aa4, bw[4], acc0);  acc1 = MF(aa5, bw[5], acc1);
    acc2 = MF(aa6, bw[6], acc2);  acc3 = MF(aa7, bw[7], acc3);
    if (fast) { LDAF(aa0,"1024"); LDAF(aa1,"1088"); LDAF(aa2,"1152"); LDAF(aa3,"1216");
                LDAF(aa4,"1280"); LDAF(aa5,"1344"); LDAF(aa6,"1408"); LDAF(aa7,"1472"); }
    else      { LDAC(aa0,"1024"); LDAC(aa1,"1088"); LDAC(aa2,"1152"); LDAC(aa3,"1216");
                LDAC(aa4,"1280"); LDAC(aa5,"1344"); LDAC(aa6,"1408"); LDAC(aa7,"1472"); }
    SB;
    asm volatile("s_waitcnt vmcnt(8)" ::: "memory"); SB;   // G1 landed
    acc0 = MF(ab0, bw[8],  acc0); acc1 = MF(ab1, bw[9],  acc1);
    acc2 = MF(ab2, bw[10], acc2); acc3 = MF(ab3, bw[11], acc3);
    acc0 = MF(ab4, bw[12], acc0); acc1 = MF(ab5, bw[13], acc1);
    acc2 = MF(ab6, bw[14], acc2); acc3 = MF(ab7, bw[15], acc3);
    if (fast) { LDAF(ab0,"1536"); LDAF(ab1,"1600"); LDAF(ab2,"1664"); LDAF(ab3,"1728");
                LDAF(ab4,"1792"); LDAF(ab5,"1856"); LDAF(ab6,"1920"); LDAF(ab7,"1984"); }
    else      { LDAC(ab0,"1536"); LDAC(ab1,"1600"); LDAC(ab2,"1664"); LDAC(ab3,"1728");
                LDAC(ab4,"1792"); LDAC(ab5,"1856"); LDAC(ab6,"1920"); LDAC(ab7,"1984"); }
    SB;
    asm volatile("s_waitcnt vmcnt(8)" ::: "memory"); SB;   // G2 landed
    acc0 = MF(aa0, bw[16], acc0); acc1 = MF(aa1, bw[17], acc1);
    acc2 = MF(aa2, bw[18], acc2); acc3 = MF(aa3, bw[19], acc3);
    acc0 = MF(aa4, bw[20], acc0); acc1 = MF(aa5, bw[21], acc1);
    acc2 = MF(aa6, bw[22], acc2); acc3 = MF(aa7, bw[23], acc3);
    asm volatile("s_waitcnt vmcnt(0)" ::: "memory"); SB;   // G3 landed
    acc0 = MF(ab0, bw[24], acc0); acc1 = MF(ab1, bw[25], acc1);
    acc2 = MF(ab2, bw[26], acc2); acc3 = MF(ab3, bw[27], acc3);
    acc0 = MF(ab4, bw[28], acc0); acc1 = MF(ab5, bw[29], acc1);
    acc2 = MF(ab6, bw[30], acc2); acc3 = MF(ab7, bw[31], acc3);

    if (matrix == 1) { // u = U h + U_b -> hand off to r-side waves (parity dbuf)
#pragma unroll
      for (int r = 0; r < 4; ++r)
        xchg[t & 1][ntile * 256 + (q * 4 + r) * 16 + ln] =
            (acc0[r] + acc1[r]) + (acc2[r] + acc3[r]);
    }
    // ---- the ONE barrier: xchg written (lgkm drained) -> epilogue may read ----
    asm volatile("s_waitcnt lgkmcnt(0)" ::: "memory");
    SB;
    __builtin_amdgcn_s_barrier();
    SB;
    asm volatile("" ::: "memory");

    if (matrix == 0) {
      unsigned int* hb32 = (unsigned int*)(hbf + (size_t)((t + 1) & 1) * 131072);
#pragma unroll
      for (int r = 0; r < 4; ++r) {
        float u = xchg[t & 1][ntile * 256 + (q * 4 + r) * 16 + ln];
        float rv = (acc0[r] + acc1[r]) + (acc2[r] + acc3[r]) + f16_f32(fwru[r]);
        float rg = 1.0f / (1.0f + __expf(-rv));
        float pre = f16_f32(fwu[r]) + rg * u;
        float e2 = __expf(-2.0f * fabsf(pre));
        float th = (1.0f - e2) / (1.0f + e2);
        float ht = copysignf(th, pre);
        float hn = gvv[r] * ht + (1.0f - gvv[r]) * h_own[r];
        h_own[r] = hn;
        int b = b0 + q * 4 + r;
        // pack adjacent dims (n_g even|odd) into u32
        unsigned short hu = f32_f16(hn);
        unsigned short pu = (unsigned short)__shfl_xor((int)hu, 1, 64);
        if (!(ln & 1)) {
          unsigned val = (unsigned)hu | ((unsigned)pu << 16);
          unsigned* dst = &hb32[(b * 1024 + n_g) >> 1];
          if (fast) st_sc0(dst, val);                          // write-through to own-XCD L2
          else __hip_atomic_store(dst, val, __ATOMIC_RELAXED,  // write-through to IC
                                  __HIP_MEMORY_SCOPE_AGENT);
        }
        if (t == nf[r] - 1) out[(size_t)b * 1024 + n_g] = hn;
      }
      if (t < 127) {
        // drain ONLY this wave's stores, then flag immediately
        SB;
        asm volatile("s_waitcnt vmcnt(0)" ::: "memory");
        if (lane == 0) {
          if (fast) st_sc0(myf, (unsigned)(t + 1));
          else __hip_atomic_store(myf, (unsigned)(t + 1),
                                  __ATOMIC_RELAXED, __HIP_MEMORY_SCOPE_AGENT);
        }
      }
    }
    acc0[0] = bias; acc0[1] = bias; acc0[2] = bias; acc0[3] = bias;
    acc1 = zero4; acc2 = zero4; acc3 = zero4;

    if (t < 127) {
      SB;
      // fwx/g prefetch for t+1: issued BEFORE the poll; the poll's inline
      // vmcnt(0) absorbs their latency while we spin anyway
      if (matrix == 0) {
#pragma unroll
        for (int r = 0; r < 4; ++r) {
          int b = b0 + q * 4 + r;
          size_t base = (size_t)(t + 1) * 262144 + (size_t)b * 2048;
          fwru[r] = fwx[base + n_g];
          fwu[r]  = fwx[base + 1024 + n_g];
          gvv[r]  = g[b * 128 + (t + 1)];
        }
      }
      SB;
      // poll all 64 producer-wave flags (one per lane); all waves poll
      if (fast) {
        for (int it = 0;; ++it) {
          unsigned v = ((it & 7) == 7)
              ? __hip_atomic_load(fp, __ATOMIC_RELAXED, __HIP_MEMORY_SCOPE_AGENT)
              : ld_sc0(fp);
          if (__ballot(v < (unsigned)(t + 1)) == 0ull) break;
        }
      } else {
        for (;;) {
          unsigned v = __hip_atomic_load(fp, __ATOMIC_RELAXED, __HIP_MEMORY_SCOPE_AGENT);
          if (__ballot(v < (unsigned)(t + 1)) == 0ull) break;
        }
      }
    }
  }
}

extern "C" void kernel_launch(void* const* d_in, const int* in_sizes, int n_in,
                              void* d_out, int out_size, void* d_ws, size_t ws_size,
                              hipStream_t stream) {
  const float* facts     = (const float*)d_in[0]; // [128][128][1024]
  const int*   num_facts = (const int*)d_in[1];   // [128]
  const float* g         = (const float*)d_in[2]; // [128][128][1]
  const float* mem_old   = (const float*)d_in[3]; // [128][1][1024]
  const float* Wr        = (const float*)d_in[4]; // [1024][1024]
  const float* Urw       = (const float*)d_in[5];
  const float* Urb       = (const float*)d_in[6];
  const float* W         = (const float*)d_in[7];
  const float* Uw        = (const float*)d_in[8];
  const float* Ub        = (const float*)d_in[9];

  // workspace layout (f16 elements unless noted)
  unsigned short* facts_h = (unsigned short*)d_ws;        // 16,777,216
  unsigned short* wstack  = facts_h + 16777216;           //  2,097,152 ([Wr|W])
  unsigned short* fwx     = wstack + 2097152;             // 33,554,432 ([t][b][2048])
  unsigned short* hbf     = fwx + 33554432;               //    262,144 (2 x [128][1024])
  unsigned int*   flg     = (unsigned int*)(hbf + 262144);// 8*32*2*16 u32 = 32KB
  unsigned int*   xcc     = flg + 8192;                   // 8*32*32 u32 = 32KB
  float* out = (float*)d_out;

  hipMemsetAsync(flg, 0, 2 * 8 * 32 * 32 * 4, stream);    // flg + xcc
  cvt_all<<<4096, 256, 0, stream>>>(
      (const float4*)facts,   (ushort4*)facts_h,
      (const float4*)Wr,      (ushort4*)wstack,
      (const float4*)W,       (ushort4*)(wstack + 1048576),
      (const float4*)mem_old, (ushort4*)hbf);
  gemm_fw<<<dim3(128, 16), 256, 0, stream>>>(facts_h, wstack, fwx);
  gru_recur<<<256, 256, 0, stream>>>(fwx, Urw, Urb, Uw, Ub, g, mem_old, num_facts, hbf, flg, xcc, out);
}

// Round 10
// 601.002 us; speedup vs baseline: 1.5142x; 1.5142x over previous
//
#include <hip/hip_runtime.h>
#include <stdint.h>

#define AS1 __attribute__((address_space(1)))
#define AS3 __attribute__((address_space(3)))

typedef _Float16 f16x8 __attribute__((ext_vector_type(8)));
typedef float f32x4 __attribute__((ext_vector_type(4)));
typedef unsigned u32x2 __attribute__((ext_vector_type(2)));

__device__ __forceinline__ unsigned short f32_f16(float f) {
  union { _Float16 h; unsigned short u; } v; v.h = (_Float16)f; return v.u;
}
__device__ __forceinline__ float f16_f32(unsigned short u) {
  union { _Float16 h; unsigned short u; } v; v.u = u; return (float)v.h;
}
// plain staging (L1+L2 cached) — for the GEMM
__device__ __forceinline__ void gl_lds16(const unsigned short* g, unsigned short* l) {
  __builtin_amdgcn_global_load_lds((const AS1 unsigned int*)g, (AS3 unsigned int*)l, 16, 0, 0);
}
// coherent staging — bypass L1+L2, read the Infinity Cache (R6/R9-proven)
__device__ __forceinline__ void gl_lds16_coh(const unsigned short* g, unsigned short* l) {
  __builtin_amdgcn_global_load_lds((const AS1 unsigned int*)g, (AS3 unsigned int*)l, 16, 0, 17);
}
// L2 staging — bypass L1 only (fast path: reads own-XCD L2)
__device__ __forceinline__ void gl_lds16_l2(const unsigned short* g, unsigned short* l) {
  __builtin_amdgcn_global_load_lds((const AS1 unsigned int*)g, (AS3 unsigned int*)l, 16, 0, 1);
}
// sc0 scalar load: bypass L1, read own-XCD L2 (R10-proven instruction)
__device__ __forceinline__ unsigned ld_sc0(const unsigned* p) {
  unsigned v;
  asm volatile("global_load_dword %0, %1, off sc0\n\ts_waitcnt vmcnt(0)"
               : "=v"(v) : "v"(p) : "memory");
  return v;
}
// sc0 pair load: two adjacent wave-flags in one RTT
__device__ __forceinline__ u32x2 ld_sc0x2(const unsigned* p) {
  u32x2 v;
  asm volatile("global_load_dwordx2 %0, %1, off sc0\n\ts_waitcnt vmcnt(0)"
               : "=v"(v) : "v"(p) : "memory");
  return v;
}
// sc0 store: write through L1 to own-XCD L2, leave line valid there (proven)
__device__ __forceinline__ void st_sc0(unsigned* p, unsigned v) {
  asm volatile("global_store_dword %0, %1, off sc0" :: "v"(p), "v"(v) : "memory");
}

// ---------------- fused f32 -> fp16 conversion (facts, Wr, W, mem_old) ----------
__global__ void cvt_all(const float4* __restrict__ sf, ushort4* __restrict__ df,
                        const float4* __restrict__ s1, ushort4* __restrict__ d1,
                        const float4* __restrict__ s2, ushort4* __restrict__ d2,
                        const float4* __restrict__ sm, ushort4* __restrict__ dm) {
  int i = blockIdx.x * blockDim.x + threadIdx.x;
  int st = gridDim.x * blockDim.x;
  for (int k = i; k < 4751360; k += st) {
    const float4* s; ushort4* d; int off;
    if (k < 4194304)      { s = sf; d = df; off = k; }
    else if (k < 4456448) { s = s1; d = d1; off = k - 4194304; }
    else if (k < 4718592) { s = s2; d = d2; off = k - 4456448; }
    else                  { s = sm; d = dm; off = k - 4718592; }
    float4 v = s[off];
    ushort4 o;
    o.x = f32_f16(v.x); o.y = f32_f16(v.y); o.z = f32_f16(v.z); o.w = f32_f16(v.w);
    d[off] = o;
  }
}

// ---------------- phase 1: C[t][b][0:2048] = facts(b,t,:) @ [Wr|W]^T (fp16 out) ----
// BK=64 (16 K-tiles), XOR source-swizzle staging, scalar C-store (proven R9/R11).
__global__ __launch_bounds__(256, 2) void gemm_fw(
    const unsigned short* __restrict__ A,
    const unsigned short* __restrict__ Bt,
    unsigned short* __restrict__ Ct)
{
  __shared__ __align__(16) unsigned short As[128 * 64];
  __shared__ __align__(16) unsigned short Bs[128 * 64];
  const int tid = threadIdx.x;
  const int lane = tid & 63;
  const int wv = tid >> 6;
  const int q = lane >> 4, ln = lane & 15;
  const int bm = blockIdx.x, bn = blockIdx.y;
  const int wm = (wv >> 1) * 64, wn = (wv & 1) * 64;

  f32x4 acc[4][4] = {};

  for (int kt = 0; kt < 1024; kt += 64) {
    __syncthreads();
#pragma unroll
    for (int rr = 0; rr < 4; ++rr) {
      int chunk = rr * 256 + tid;          // 0..1023
      int r = chunk >> 3, c = chunk & 7;   // 8 chunks (16B) per 128B row
      int cs = c ^ (r & 7);                // source chunk for this LDS pos
      gl_lds16(A + (size_t)(bm * 128 + r) * 1024 + kt + cs * 8, As + chunk * 8);
      gl_lds16(Bt + (size_t)(bn * 128 + r) * 1024 + kt + cs * 8, Bs + chunk * 8);
    }
    __syncthreads();
    f16x8 af[4][2], bfr[4][2];
#pragma unroll
    for (int mi = 0; mi < 4; ++mi)
#pragma unroll
      for (int kk = 0; kk < 2; ++kk)
        af[mi][kk] = *(const f16x8*)(As + (wm + mi * 16 + ln) * 64 + (((q + 4 * kk) ^ (ln & 7)) * 8));
#pragma unroll
    for (int ni = 0; ni < 4; ++ni)
#pragma unroll
      for (int kk = 0; kk < 2; ++kk)
        bfr[ni][kk] = *(const f16x8*)(Bs + (wn + ni * 16 + ln) * 64 + (((q + 4 * kk) ^ (ln & 7)) * 8));
#pragma unroll
    for (int kk = 0; kk < 2; ++kk)
#pragma unroll
      for (int mi = 0; mi < 4; ++mi)
#pragma unroll
        for (int ni = 0; ni < 4; ++ni)
          acc[mi][ni] = __builtin_amdgcn_mfma_f32_16x16x32_f16(af[mi][kk], bfr[ni][kk], acc[mi][ni], 0, 0, 0);
  }
#pragma unroll
  for (int mi = 0; mi < 4; ++mi)
#pragma unroll
    for (int ni = 0; ni < 4; ++ni)
#pragma unroll
      for (int r2 = 0; r2 < 4; ++r2) {
        int trow = wm + mi * 16 + q * 4 + r2;   // == t
        int col = bn * 128 + wn + ni * 16 + ln; // 0..2047: [fWr | fW]
        Ct[(size_t)trow * 262144 + (size_t)bm * 2048 + col] = f32_f16(acc[mi][ni][r2]);
      }
}

// ---------------- phase 2: the recurrence (fused r|u MFMA, 1 barrier/step) ----
// Grid 256 = 8 groups x 32 dim-slices; 4 symmetric waves per block, each owns
// 8 dims x BOTH matrices: B-fragment lanes ln<8 = Ur rows, ln>=8 = U rows for
// the same 8 dims -> output col ln = r-preact, col ln+8 = u-preact. The r/u
// pairing is an in-wave shfl_xor(8) -> the xchg LDS + barrier A are DELETED.
// The bottom poll subsumes barrier A: no wave passes it until all 128 group
// wave-flags (incl. our own block's) hit t+1, and a wave flags only after its
// MFMA consumed At(t). One s_barrier/step (staging handoff). All waves run the
// epilogue (8 dims each) and flag per-wave right after their own store-ack ->
// 128 flags/group, polled as 64 dwordx2 pairs. Staging + ride-through fwx
// order is R5-proven: poll -> stage(8) -> fwx(12) -> vmcnt(12) -> barrier.
#define MF(A_, B_, C_) __builtin_amdgcn_mfma_f32_16x16x32_f16(A_, B_, C_, 0, 0, 0)
#define SB __builtin_amdgcn_sched_barrier(0)

__global__ __launch_bounds__(256, 1) void gru_recur(
    const unsigned short* __restrict__ fwx,   // [128 t][128 b][2048] f16
    const float* __restrict__ Urw, const float* __restrict__ Urb,
    const float* __restrict__ Uw,  const float* __restrict__ Ub,
    const float* __restrict__ g,              // [128 b][128 t]
    const float* __restrict__ mem_old,        // [128][1024]
    const int* __restrict__ nfp,              // [128]
    unsigned short* __restrict__ hbf,         // [2][128][1024] f16
    unsigned int* __restrict__ flg,           // [8 ga][64 pair][16 pad] u32
    unsigned int* __restrict__ xcc,           // [8 ga][32 blk][32 pad] u32
    float* __restrict__ out)                  // [128][1024] f32
{
  __shared__ __align__(16) unsigned char At[32768]; // 16 rows x 2048B, dense
  __shared__ int fast_lds;

  const int tid = threadIdx.x;
  const int lane = tid & 63;
  const int w = tid >> 6;           // wave 0..3: dims dsl*32 + w*8 .. +8
  const int q = lane >> 4;
  const int ln = lane & 15;
  const int ga = blockIdx.x & 7;    // XCD-local group under round-robin dispatch
  const int dsl = blockIdx.x >> 3;  // dim-slice within group, 0..31
  const int b0 = ga * 16;
  const int dim = dsl * 32 + w * 8 + (ln & 7);   // this lane's output dim
  const int rside = (ln < 8);

  // --- XCD-uniformity handshake (R10-proven, over the always-correct IC path) ---
  unsigned my_xcc;
  asm("s_getreg_b32 %0, hwreg(HW_REG_XCC_ID)" : "=s"(my_xcc));
  if (tid == 0)
    __hip_atomic_store(&xcc[(ga * 32 + dsl) * 32], my_xcc + 1u,
                       __ATOMIC_RELAXED, __HIP_MEMORY_SCOPE_AGENT);
  if (w == 0) {
    unsigned* xp = &xcc[(ga * 32 + (lane & 31)) * 32];
    unsigned v;
    for (;;) {
      v = __hip_atomic_load(xp, __ATOMIC_RELAXED, __HIP_MEMORY_SCOPE_AGENT);
      if (__ballot(lane < 32 && v == 0u) == 0ull) break;
    }
    unsigned long long bad = __ballot(lane < 32 && v != my_xcc + 1u);
    if (lane == 0) fast_lds = (bad == 0ull);
  }

  // --- one-time: fused B-fragment: lanes ln<8 carry Ur[dim], ln>=8 carry U[dim] ---
  const float* Wm = rside ? Urw : Uw;
  f16x8 bw[32];
#pragma unroll
  for (int ks = 0; ks < 32; ++ks) {
    const float* s = Wm + (size_t)dim * 1024 + ks * 32 + q * 8;
    float4 x0 = *(const float4*)s;
    float4 x1 = *(const float4*)(s + 4);
    f16x8 t;
    t[0] = (_Float16)x0.x; t[1] = (_Float16)x0.y;
    t[2] = (_Float16)x0.z; t[3] = (_Float16)x0.w;
    t[4] = (_Float16)x1.x; t[5] = (_Float16)x1.y;
    t[6] = (_Float16)x1.z; t[7] = (_Float16)x1.w;
    bw[ks] = t;
  }
  const float bias = (rside ? Urb : Ub)[dim];
  const f32x4 zero4 = {0.f, 0.f, 0.f, 0.f};
  f32x4 acc0 = {bias, bias, bias, bias};   // ks%4==0 chain (carries the bias)
  f32x4 acc1 = zero4, acc2 = zero4, acc3 = zero4;

  float h_own[4] = {0.f, 0.f, 0.f, 0.f};
  int nf[4] = {0, 0, 0, 0};
  if (rside) {
#pragma unroll
    for (int r = 0; r < 4; ++r) {
      int b = b0 + q * 4 + r;
      h_own[r] = mem_old[(size_t)b * 1024 + dim];
      nf[r] = nfp[b];
    }
  }

  __syncthreads();
  const int fast = fast_lds;

  // A-fragment read bases: row ln (pitch 2048), chunk(ks) = (q + 4*ks) ^ (ln&7).
  const int swz = ln & 7;
  const int rowb = ln * 2048 + (q ^ (swz & 3)) * 16;
  const int be = rowb + ((swz >> 2) << 6);        // ks even
  const int bo = rowb + (((swz >> 2) ^ 1) << 6);  // ks odd

  // per-WAVE flag: pair pp = dsl*2 + (w>>1), slot w&1. Consumer lane l polls
  // pair l (dwordx2 = 2 wave-flags in one RTT); 64 lanes cover all 128 waves.
  unsigned int* myf = flg + ((size_t)(ga * 64 + dsl * 2 + (w >> 1))) * 16 + (w & 1);
  unsigned int* fp  = flg + ((size_t)(ga * 64 + lane)) * 16;

  // epilogue operands carried as RAW u16 (loads ride through barrier + MFMA)
  unsigned short fwru[4] = {0, 0, 0, 0}, fwu[4] = {0, 0, 0, 0};
  float gvv[4] = {0.f, 0.f, 0.f, 0.f};

  // --- prologue: mirror of the loop bottom for t=0 (h(0)=mem_old via cvt_all) ---
  {
    const unsigned short* hsrc = hbf + (size_t)b0 * 1024;
    if (fast) {
#pragma unroll
      for (int j = 0; j < 8; ++j) {
        int blk = w * 8 + j;
        int m = blk >> 1, kh = blk & 1;
        gl_lds16_l2(hsrc + m * 1024 + kh * 512 + ((lane ^ (m & 7)) * 8),
                    (unsigned short*)(At + m * 2048 + kh * 1024));
      }
    } else {
#pragma unroll
      for (int j = 0; j < 8; ++j) {
        int blk = w * 8 + j;
        int m = blk >> 1, kh = blk & 1;
        gl_lds16_coh(hsrc + m * 1024 + kh * 512 + ((lane ^ (m & 7)) * 8),
                     (unsigned short*)(At + m * 2048 + kh * 1024));
      }
    }
    SB;
    if (rside) {  // fwx(0): 12 loads, youngest — ride through the barrier
#pragma unroll
      for (int r = 0; r < 4; ++r) {
        int b = b0 + q * 4 + r;
        size_t base = (size_t)b * 2048;   // t = 0
        fwru[r] = fwx[base + dim];
        fwu[r]  = fwx[base + 1024 + dim];
        gvv[r]  = g[b * 128 + 0];
      }
    }
    SB;
    asm volatile("s_waitcnt vmcnt(12)" ::: "memory"); // drain the 8 staging only
    SB;
    __builtin_amdgcn_s_barrier();
    SB;
    asm volatile("" ::: "memory");
  }

  for (int t = 0; t < 128; ++t) {
    // entry invariant: At(t) fully staged (barrier / prologue); fwx(t) in
    // flight or done, consumed in the epilogue via compiler-inserted waits.

    // MFMA: ks 0..31 from LDS, 4 independent chains (r|u fused in columns)
#pragma unroll
    for (int ks = 0; ks < 32; ++ks) {
      const unsigned char* ap = At + (((ks & 1) ? bo : be) + ((ks >> 1) << 7));
      f16x8 a = *(const f16x8*)ap;
      switch (ks & 3) {
        case 0: acc0 = MF(a, bw[ks], acc0); break;
        case 1: acc1 = MF(a, bw[ks], acc1); break;
        case 2: acc2 = MF(a, bw[ks], acc2); break;
        default: acc3 = MF(a, bw[ks], acc3); break;
      }
    }

    // r/u pairing: col ln holds r-preact, col ln+8 holds u-preact -> shfl_xor(8)
    float accsum[4], uval[4];
#pragma unroll
    for (int r = 0; r < 4; ++r) {
      accsum[r] = (acc0[r] + acc1[r]) + (acc2[r] + acc3[r]);
      uval[r] = __shfl_xor(accsum[r], 8, 64);   // all lanes participate
    }

    // epilogue: lanes ln<8 own (4 batches x 1 dim); no block sync needed
    if (rside) {
      unsigned int* hb32 = (unsigned int*)(hbf + (size_t)((t + 1) & 1) * 131072);
#pragma unroll
      for (int r = 0; r < 4; ++r) {
        float rv = accsum[r] + f16_f32(fwru[r]);
        float rg = 1.0f / (1.0f + __expf(-rv));
        float pre = f16_f32(fwu[r]) + rg * uval[r];
        float e2 = __expf(-2.0f * fabsf(pre));
        float th = (1.0f - e2) / (1.0f + e2);
        float ht = copysignf(th, pre);
        float hn = gvv[r] * ht + (1.0f - gvv[r]) * h_own[r];
        h_own[r] = hn;
        int b = b0 + q * 4 + r;
        // pack adjacent dims (ln even|odd) into u32
        unsigned short hu = f32_f16(hn);
        unsigned short pu = (unsigned short)__shfl_xor((int)hu, 1, 64);
        if (!(ln & 1)) {
          unsigned val = (unsigned)hu | ((unsigned)pu << 16);
          unsigned* dst = &hb32[(b * 1024 + dim) >> 1];
          if (fast) st_sc0(dst, val);                          // write-through to own-XCD L2
          else __hip_atomic_store(dst, val, __ATOMIC_RELAXED,  // write-through to IC
                                  __HIP_MEMORY_SCOPE_AGENT);
        }
        if (t == nf[r] - 1) out[(size_t)b * 1024 + dim] = hn;
      }
    }
    acc0[0] = bias; acc0[1] = bias; acc0[2] = bias; acc0[3] = bias;
    acc1 = zero4; acc2 = zero4; acc3 = zero4;

    if (t < 127) {
      // drain THIS wave's h stores, then publish this wave's flag immediately
      SB;
      asm volatile("s_waitcnt vmcnt(0)" ::: "memory");
      SB;
      if (lane == 0) {
        if (fast) st_sc0(myf, (unsigned)(t + 1));
        else __hip_atomic_store(myf, (unsigned)(t + 1),
                                __ATOMIC_RELAXED, __HIP_MEMORY_SCOPE_AGENT);
      }

      // poll all 128 producer-wave flags (2 per lane via dwordx2)
      unsigned thr = (unsigned)(t + 1);
      if (fast) {
        for (int it = 0;; ++it) {
          u32x2 v;
          if ((it & 7) == 7) {
            v[0] = __hip_atomic_load(fp,     __ATOMIC_RELAXED, __HIP_MEMORY_SCOPE_AGENT);
            v[1] = __hip_atomic_load(fp + 1, __ATOMIC_RELAXED, __HIP_MEMORY_SCOPE_AGENT);
          } else {
            v = ld_sc0x2(fp);
          }
          if (__ballot(v[0] < thr || v[1] < thr) == 0ull) break;
        }
      } else {
        for (;;) {
          unsigned v0 = __hip_atomic_load(fp,     __ATOMIC_RELAXED, __HIP_MEMORY_SCOPE_AGENT);
          unsigned v1 = __hip_atomic_load(fp + 1, __ATOMIC_RELAXED, __HIP_MEMORY_SCOPE_AGENT);
          if (__ballot(v0 < thr || v1 < thr) == 0ull) break;
        }
      }

      // stage h(t+1): 8 chunks per wave (oldest vm ops after the poll)
      const unsigned short* hsrcN = hbf + (size_t)((t + 1) & 1) * 131072 + (size_t)b0 * 1024;
      if (fast) {
#pragma unroll
        for (int j = 0; j < 8; ++j) {
          int blk = w * 8 + j;
          int m = blk >> 1, kh = blk & 1;
          gl_lds16_l2(hsrcN + m * 1024 + kh * 512 + ((lane ^ (m & 7)) * 8),
                      (unsigned short*)(At + m * 2048 + kh * 1024));
        }
      } else {
#pragma unroll
        for (int j = 0; j < 8; ++j) {
          int blk = w * 8 + j;
          int m = blk >> 1, kh = blk & 1;
          gl_lds16_coh(hsrcN + m * 1024 + kh * 512 + ((lane ^ (m & 7)) * 8),
                       (unsigned short*)(At + m * 2048 + kh * 1024));
        }
      }
      SB;

      // fwx/g prefetch for t+1 (12 loads, youngest): ride through the barrier
      // + next MFMA phase, consumed in the next epilogue via compiler waits
      if (rside) {
#pragma unroll
        for (int r = 0; r < 4; ++r) {
          int b = b0 + q * 4 + r;
          size_t base = (size_t)(t + 1) * 262144 + (size_t)b * 2048;
          fwru[r] = fwx[base + dim];
          fwu[r]  = fwx[base + 1024 + dim];
          gvv[r]  = g[b * 128 + (t + 1)];
        }
      }
      SB;

      // ---- the ONE barrier: staging drained (counted — fwx stays in flight) ----
      asm volatile("s_waitcnt vmcnt(12)" ::: "memory");
      SB;
      __builtin_amdgcn_s_barrier();
      SB;
      asm volatile("" ::: "memory");
    }
  }
}

extern "C" void kernel_launch(void* const* d_in, const int* in_sizes, int n_in,
                              void* d_out, int out_size, void* d_ws, size_t ws_size,
                              hipStream_t stream) {
  const float* facts     = (const float*)d_in[0]; // [128][128][1024]
  const int*   num_facts = (const int*)d_in[1];   // [128]
  const float* g         = (const float*)d_in[2]; // [128][128][1]
  const float* mem_old   = (const float*)d_in[3]; // [128][1][1024]
  const float* Wr        = (const float*)d_in[4]; // [1024][1024]
  const float* Urw       = (const float*)d_in[5];
  const float* Urb       = (const float*)d_in[6];
  const float* W         = (const float*)d_in[7];
  const float* Uw        = (const float*)d_in[8];
  const float* Ub        = (const float*)d_in[9];

  // workspace layout (f16 elements unless noted)
  unsigned short* facts_h = (unsigned short*)d_ws;        // 16,777,216
  unsigned short* wstack  = facts_h + 16777216;           //  2,097,152 ([Wr|W])
  unsigned short* fwx     = wstack + 2097152;             // 33,554,432 ([t][b][2048])
  unsigned short* hbf     = fwx + 33554432;               //    262,144 (2 x [128][1024])
  unsigned int*   flg     = (unsigned int*)(hbf + 262144);// 8*64*16 u32 = 32KB
  unsigned int*   xcc     = flg + 8192;                   // 8*32*32 u32 = 32KB
  float* out = (float*)d_out;

  hipMemsetAsync(flg, 0, 2 * 8 * 32 * 32 * 4, stream);    // flg + xcc
  cvt_all<<<4096, 256, 0, stream>>>(
      (const float4*)facts,   (ushort4*)facts_h,
      (const float4*)Wr,      (ushort4*)wstack,
      (const float4*)W,       (ushort4*)(wstack + 1048576),
      (const float4*)mem_old, (ushort4*)hbf);
  gemm_fw<<<dim3(128, 16), 256, 0, stream>>>(facts_h, wstack, fwx);
  gru_recur<<<256, 256, 0, stream>>>(fwx, Urw, Urb, Uw, Ub, g, mem_old, num_facts, hbf, flg, xcc, out);
}